// Round 1
// baseline (1360.095 us; speedup 1.0000x reference)
//
#include <hip/hip_runtime.h>
#include <stdint.h>

#define DICT  24576
#define BLOCK 1024
#define PER   24          // DICT / BLOCK elements per thread
#define NV    6           // float4 loads per thread
#define EQCAP 256

// order-preserving float -> uint32 key (ascending)
__device__ __forceinline__ uint32_t f2key(float f) {
    uint32_t u = __float_as_uint(f);
    return (u & 0x80000000u) ? ~u : (u | 0x80000000u);
}
__device__ __forceinline__ float key2f(uint32_t kk) {
    uint32_t u = (kk & 0x80000000u) ? (kk ^ 0x80000000u) : ~kk;
    return __uint_as_float(u);
}

// One radix pass: histogram NB buckets of key bits [LO+NBITS-1 : LO] for
// elements matching the current prefix, then find the bucket containing the
// r-th largest. Updates prefix (appends NBITS) and r (count still needed
// inside the chosen bucket).
template<int LO, int NBITS, bool FIRST>
__device__ __forceinline__ void radix_pass(const uint32_t (&key)[PER],
                                           uint32_t* hist,
                                           uint32_t* s_bstar,
                                           uint32_t* s_r,
                                           uint32_t& prefix, uint32_t& r,
                                           int tid) {
    constexpr int NB = 1 << NBITS;
    constexpr int PER_SEG = NB / 64;

    __syncthreads();                         // protect hist from prior readers
    for (int i = tid; i < NB; i += BLOCK) hist[i] = 0;
    __syncthreads();

    #pragma unroll
    for (int e = 0; e < PER; ++e) {
        uint32_t kk = key[e];
        bool part = FIRST ? true : ((kk >> (LO + NBITS)) == prefix);
        if (part) {
            uint32_t b = (kk >> LO) & (NB - 1);
            atomicAdd(&hist[b], 1u);
        }
    }
    __syncthreads();

    if (tid < 64) {
        // per-lane segment sum; rotate the read index so lanes don't all hit
        // bank 0 (stride PER_SEG*4B would otherwise be a 64-way conflict)
        uint32_t segsum = 0;
        #pragma unroll
        for (int i = 0; i < PER_SEG; ++i) {
            int idx = tid * PER_SEG + ((i + tid) & (PER_SEG - 1));
            segsum += hist[idx];
        }
        // inclusive suffix sum over 64 lanes (lane l = count of buckets >= seg l)
        uint32_t S = segsum;
        #pragma unroll
        for (int off = 1; off < 64; off <<= 1) {
            uint32_t v = __shfl_down(S, off, 64);
            if (tid + off < 64) S += v;
        }
        uint32_t A = S - segsum;             // strictly above this segment
        bool cross = (A < r) && (S >= r);    // exactly one lane true
        unsigned long long m = __ballot(cross);
        int seg = __ffsll(m) - 1;
        uint32_t aboveSeg = __shfl(A, seg, 64);
        // resolve inside the crossing segment (PER_SEG buckets, lanes 0..PER_SEG-1)
        uint32_t h = 0;
        if (tid < PER_SEG) h = hist[seg * PER_SEG + tid];
        uint32_t S2 = h;
        #pragma unroll
        for (int off = 1; off < PER_SEG; off <<= 1) {
            uint32_t v = __shfl_down(S2, off, 64);
            if (tid + off < PER_SEG) S2 += v;
        }
        uint32_t A2 = aboveSeg + S2 - h;     // strictly above bucket b
        if (tid < PER_SEG && A2 < r && A2 + h >= r) {
            *s_bstar = (uint32_t)(seg * PER_SEG + tid);
            *s_r = r - A2;
        }
    }
    __syncthreads();
    prefix = (prefix << NBITS) | *s_bstar;
    r = *s_r;
}

__global__ __launch_bounds__(BLOCK) void topk_kernel(const float* __restrict__ z,
                                                     const int* __restrict__ kp,
                                                     float* __restrict__ out) {
    __shared__ uint32_t hist[2048];
    __shared__ uint32_t s_bstar, s_r, eqCount;
    __shared__ uint32_t eqIdx[EQCAP];

    const int tid = threadIdx.x;
    const int row = blockIdx.x;
    const uint32_t k = (uint32_t)kp[0];

    const float4* zr = (const float4*)(z + (size_t)row * DICT);
    float4* outr = (float4*)(out + (size_t)row * DICT);

    // one global read: 6 coalesced float4 per thread, keys kept in registers
    uint32_t key[PER];
    #pragma unroll
    for (int j = 0; j < NV; ++j) {
        float4 v = zr[j * BLOCK + tid];
        key[j*4+0] = f2key(v.x);
        key[j*4+1] = f2key(v.y);
        key[j*4+2] = f2key(v.z);
        key[j*4+3] = f2key(v.w);
    }

    uint32_t prefix = 0, r = k;
    radix_pass<21, 11, true >(key, hist, &s_bstar, &s_r, prefix, r, tid);
    radix_pass<10, 11, false>(key, hist, &s_bstar, &s_r, prefix, r, tid);
    radix_pass< 0, 10, false>(key, hist, &s_bstar, &s_r, prefix, r, tid);
    const uint32_t T = prefix;   // exact key of the k-th largest
    // r = number of key==T elements to keep (stable: lowest indices first)

    if (tid == 0) eqCount = 0;
    __syncthreads();
    #pragma unroll
    for (int e = 0; e < PER; ++e) {
        if (key[e] == T) {
            uint32_t slot = atomicAdd(&eqCount, 1u);
            if (slot < EQCAP) {
                int j = e >> 2, c = e & 3;
                eqIdx[slot] = (uint32_t)(j * 4096 + tid * 4 + c);
            }
        }
    }
    __syncthreads();
    const uint32_t ec = eqCount < EQCAP ? eqCount : EQCAP;

    // one global write: selected values at original positions, zeros elsewhere
    #pragma unroll
    for (int j = 0; j < NV; ++j) {
        float vals[4];
        #pragma unroll
        for (int c = 0; c < 4; ++c) {
            uint32_t kk = key[j*4 + c];
            float val = 0.0f;
            if (kk > T) {
                val = key2f(kk);
            } else if (kk == T) {
                uint32_t gi = (uint32_t)(j * 4096 + tid * 4 + c);
                uint32_t rank = 0;
                for (uint32_t i = 0; i < ec; ++i) rank += (eqIdx[i] < gi) ? 1u : 0u;
                if (rank < r) val = key2f(kk);
            }
            vals[c] = val;
        }
        float4 o;
        o.x = vals[0]; o.y = vals[1]; o.z = vals[2]; o.w = vals[3];
        outr[j * BLOCK + tid] = o;
    }
}

extern "C" void kernel_launch(void* const* d_in, const int* in_sizes, int n_in,
                              void* d_out, int out_size, void* d_ws, size_t ws_size,
                              hipStream_t stream) {
    const float* z = (const float*)d_in[0];
    const int*   kp = (const int*)d_in[1];
    float* out = (float*)d_out;
    const int batch = in_sizes[0] / DICT;
    topk_kernel<<<dim3(batch), dim3(BLOCK), 0, stream>>>(z, kp, out);
}